// Round 2
// baseline (1263.831 us; speedup 1.0000x reference)
//
#include <hip/hip_runtime.h>
#include <hip/hip_bf16.h>

// Problem constants
#define BB   2
#define SS   2048
#define DD   2560
#define HH   8
#define HKVV 4
#define HDD  256
#define MM   (BB*SS)      // 4096 rows
#define NQ   (HH*HDD)     // 2048
#define NKV  (HKVV*HDD)   // 1024
#define SCALING 0.0625f   // 256^-0.5
#define SOFTCAP 4096.0f

typedef __attribute__((ext_vector_type(8))) short short8;       // 8 bf16 (4 VGPR)
typedef __attribute__((ext_vector_type(8))) unsigned short ushort8;
typedef __attribute__((ext_vector_type(4))) float f32x4;        // MFMA C/D

__device__ __forceinline__ float bf2f(unsigned short u) {
    union { unsigned int i; float f; } v; v.i = ((unsigned int)u) << 16; return v.f;
}
__device__ __forceinline__ unsigned short f2bf(float f) {
    union { float f; unsigned int i; } v; v.f = f;
    return (unsigned short)((v.i + 0x7fffu + ((v.i >> 16) & 1u)) >> 16);
}
__device__ __forceinline__ f32x4 mfma16(short8 a, short8 b, f32x4 c) {
    return __builtin_amdgcn_mfma_f32_16x16x32_bf16(a, b, c, 0, 0, 0);
}

// dtype-polymorphic 8-element load (→ bf16x8) and scalar store
__device__ __forceinline__ ushort8 ld8(const unsigned short* p) { return *(const ushort8*)p; }
__device__ __forceinline__ ushort8 ld8(const float* p) {
    ushort8 r;
#pragma unroll
    for (int i = 0; i < 8; i++) r[i] = f2bf(p[i]);
    return r;
}
__device__ __forceinline__ void stc(float* p, float v)          { *p = v; }
__device__ __forceinline__ void stc(unsigned short* p, float v) { *p = f2bf(v); }

// ---------------------------------------------------------------------------
// C(M,N) = A(M,K) @ B(N,K)^T. A/B converted to bf16 in LDS staging, fp32
// accum. 128x128 tile, 4 waves, each wave 64x64 = 4x4 MFMA tiles, BK=32.
// ---------------------------------------------------------------------------
template<typename TA, typename TB, typename TC>
__global__ __launch_bounds__(256) void gemm_bt(const TA* __restrict__ A,
                                               const TB* __restrict__ Bm,
                                               TC* __restrict__ C,
                                               int M, int N, int K)
{
    __shared__ __align__(16) unsigned short As[128][40];  // +8 pad: break 16-stride
    __shared__ __align__(16) unsigned short Bs[128][40];

    const int tid  = threadIdx.x;
    const int bm   = blockIdx.x, bn = blockIdx.y;
    const int wave = tid >> 6, lane = tid & 63;
    const int quad = lane >> 4, lm = lane & 15;
    const int wm = (wave >> 1) * 64, wn = (wave & 1) * 64;

    f32x4 acc[4][4];
#pragma unroll
    for (int i = 0; i < 4; i++)
#pragma unroll
        for (int j = 0; j < 4; j++) acc[i][j] = (f32x4)0.0f;

    const int srow = tid >> 2;           // 0..63
    const int sch  = (tid & 3) * 8;      // 0,8,16,24
    const TA* Ab = A  + (size_t)(bm * 128) * K;
    const TB* Bb = Bm + (size_t)(bn * 128) * K;

    for (int k0 = 0; k0 < K; k0 += 32) {
        *(ushort8*)&As[srow     ][sch] = ld8(&Ab[(size_t)(srow     ) * K + k0 + sch]);
        *(ushort8*)&As[srow + 64][sch] = ld8(&Ab[(size_t)(srow + 64) * K + k0 + sch]);
        *(ushort8*)&Bs[srow     ][sch] = ld8(&Bb[(size_t)(srow     ) * K + k0 + sch]);
        *(ushort8*)&Bs[srow + 64][sch] = ld8(&Bb[(size_t)(srow + 64) * K + k0 + sch]);
        __syncthreads();

        short8 af[4], bf[4];
#pragma unroll
        for (int t = 0; t < 4; t++) af[t] = *(const short8*)&As[wm + t * 16 + lm][quad * 8];
#pragma unroll
        for (int t = 0; t < 4; t++) bf[t] = *(const short8*)&Bs[wn + t * 16 + lm][quad * 8];
#pragma unroll
        for (int i = 0; i < 4; i++)
#pragma unroll
            for (int j = 0; j < 4; j++)
                acc[i][j] = mfma16(af[i], bf[j], acc[i][j]);
        __syncthreads();
    }

    // C/D layout: row = quad*4 + r, col = lm  [verified m89/m91]
#pragma unroll
    for (int i = 0; i < 4; i++)
#pragma unroll
        for (int j = 0; j < 4; j++)
#pragma unroll
            for (int r = 0; r < 4; r++) {
                int row = bm * 128 + wm + i * 16 + quad * 4 + r;
                int col = bn * 128 + wn + j * 16 + lm;
                stc(&C[(size_t)row * N + col], acc[i][j][r]);
            }
}

// ---------------------------------------------------------------------------
// Fused RMSNorm + RoPE in place on bf16 X laid out (b, s, h, d), one block
// per (bs, h) row of HD=256. cos/sin/nw are fp32.
// ---------------------------------------------------------------------------
__global__ __launch_bounds__(256) void norm_rope(unsigned short* __restrict__ X,
                                                 const float* __restrict__ nw,
                                                 const float* __restrict__ cosb,
                                                 const float* __restrict__ sinb,
                                                 int nheads)
{
    const int bs = blockIdx.x;   // 0..B*S-1
    const int h  = blockIdx.y;
    const int t  = threadIdx.x;  // 0..255

    __shared__ float xs[256];
    __shared__ float red[4];

    const size_t base = ((size_t)bs * nheads + h) * HDD;
    float v = bf2f(X[base + t]);
    xs[t] = v;

    float p = v * v;
#pragma unroll
    for (int off = 32; off >= 1; off >>= 1) p += __shfl_xor(p, off);
    if ((t & 63) == 0) red[t >> 6] = p;
    __syncthreads();
    float sum = red[0] + red[1] + red[2] + red[3];
    float rs  = rsqrtf(sum * (1.0f / HDD) + 1e-6f);

    const int pt = (t + 128) & 255;
    float w1 = 1.0f + nw[t];
    float w2 = 1.0f + nw[pt];
    float normed  = v * rs * w1;
    float partner = xs[pt] * rs * w2;
    float rot = (t < 128) ? -partner : partner;   // rotate_half: [-x2, x1]
    float c = cosb[(size_t)bs * HDD + t];
    float s = sinb[(size_t)bs * HDD + t];
    X[base + t] = f2bf(normed * c + rot * s);
}

// ---------------------------------------------------------------------------
// Flash attention, causal, GQA (q head h -> kv head h/2), softcap.
// Block = 256 thr = 4 waves, TQ=64 q-rows (16/wave), TK=32 keys staged in LDS.
// Q,K,V ws layout (b,s,h,d) bf16; out ATT layout (b,s, h*HD+d) bf16.
// ---------------------------------------------------------------------------
#define TQ 64
#define TK 32

__global__ __launch_bounds__(256) void attn_kernel(const unsigned short* __restrict__ Q,
                                                   const unsigned short* __restrict__ Kw,
                                                   const unsigned short* __restrict__ Vw,
                                                   unsigned short* __restrict__ O)
{
    const int q0  = blockIdx.x * TQ;
    const int h   = blockIdx.y;
    const int b   = blockIdx.z;
    const int kvh = h >> 1;                       // H/HKV == 2
    const int tid = threadIdx.x, w = tid >> 6, lane = tid & 63;
    const int quad = lane >> 4, lm = lane & 15;

    __shared__ __align__(16) unsigned short Ks[TK][264];   // pad: 4-bank row step
    __shared__ __align__(16) unsigned short Vt[HDD][40];   // transposed V, pad 40
    __shared__ __align__(16) unsigned short Ps[4][16][32]; // per-wave P round-trip

    // Q A-fragments for this wave's 16 rows: lane holds Q[row=lm][k=quad*8+j]
    const int qrow = q0 + w * 16 + lm;
    const unsigned short* Qb = Q + (((size_t)b * SS + qrow) * HH + h) * HDD;
    short8 qf[8];
#pragma unroll
    for (int c = 0; c < 8; c++) qf[c] = *(const short8*)&Qb[c * 32 + quad * 8];

    f32x4 o_acc[16];
#pragma unroll
    for (int i = 0; i < 16; i++) o_acc[i] = (f32x4)0.0f;
    float m_r[4], l_r[4];
#pragma unroll
    for (int r = 0; r < 4; r++) { m_r[r] = -1e30f; l_r[r] = 0.0f; }

    const int wmax = q0 + w * 16 + 15;
    const int nkt  = (q0 + TQ + TK - 1) / TK;

    for (int kt = 0; kt < nkt; kt++) {
        const int k0 = kt * TK;
        // ---- stage K (row-major) and V (transposed) ----
#pragma unroll
        for (int pass = 0; pass < 4; pass++) {
            int c   = tid + pass * 256;          // 0..1023
            int key = c >> 5;
            int ch8 = (c & 31) * 8;
            const size_t gb = (((size_t)b * SS + k0 + key) * HKVV + kvh) * HDD;
            *(ushort8*)&Ks[key][ch8] = *(const ushort8*)&Kw[gb + ch8];
            ushort8 vv = *(const ushort8*)&Vw[gb + ch8];
#pragma unroll
            for (int n = 0; n < 8; n++) {        // lane-rotated to cut bank conflicts
                int i = (n + tid) & 7;
                Vt[ch8 + i][key] = vv[i];
            }
        }
        __syncthreads();

        if (k0 <= wmax) {
            // ---- scores S = Q K^T (16 x 32) ----
            f32x4 sa[2];
            sa[0] = (f32x4)0.0f; sa[1] = (f32x4)0.0f;
#pragma unroll
            for (int c = 0; c < 8; c++) {
                short8 b0 = *(const short8*)&Ks[lm     ][c * 32 + quad * 8];
                short8 b1 = *(const short8*)&Ks[16 + lm][c * 32 + quad * 8];
                sa[0] = mfma16(qf[c], b0, sa[0]);
                sa[1] = mfma16(qf[c], b1, sa[1]);
            }

            // ---- scale, softcap, causal mask, online softmax ----
            const int row_base = q0 + w * 16 + quad * 4;
            float pv[2][4], mt[4];
#pragma unroll
            for (int r = 0; r < 4; r++) mt[r] = -1e30f;
#pragma unroll
            for (int t = 0; t < 2; t++) {
                int key = k0 + t * 16 + lm;
#pragma unroll
                for (int r = 0; r < 4; r++) {
                    float s = sa[t][r] * SCALING;
                    s = tanhf(s * (1.0f / SOFTCAP)) * SOFTCAP;
                    if (key > row_base + r) s = -1e30f;
                    pv[t][r] = s;
                    mt[r] = fmaxf(mt[r], s);
                }
            }
#pragma unroll
            for (int off = 1; off < 16; off <<= 1)
#pragma unroll
                for (int r = 0; r < 4; r++) mt[r] = fmaxf(mt[r], __shfl_xor(mt[r], off));

            float alpha[4];
#pragma unroll
            for (int r = 0; r < 4; r++) {
                float mn = fmaxf(m_r[r], mt[r]);
                alpha[r] = expf(m_r[r] - mn);    // first tile: exp(-1e30-x) -> 0
                m_r[r] = mn;
            }
            float sums[4] = {0.f, 0.f, 0.f, 0.f};
#pragma unroll
            for (int t = 0; t < 2; t++)
#pragma unroll
                for (int r = 0; r < 4; r++) {
                    float e = expf(pv[t][r] - m_r[r]);
                    pv[t][r] = e;
                    sums[r] += e;
                }
#pragma unroll
            for (int off = 1; off < 16; off <<= 1)
#pragma unroll
                for (int r = 0; r < 4; r++) sums[r] += __shfl_xor(sums[r], off);
#pragma unroll
            for (int r = 0; r < 4; r++) l_r[r] = l_r[r] * alpha[r] + sums[r];
#pragma unroll
            for (int i = 0; i < 16; i++)
#pragma unroll
                for (int r = 0; r < 4; r++) o_acc[i][r] *= alpha[r];

            // ---- P: C layout -> A layout via per-wave LDS round-trip ----
#pragma unroll
            for (int t = 0; t < 2; t++)
#pragma unroll
                for (int r = 0; r < 4; r++)
                    Ps[w][quad * 4 + r][t * 16 + lm] = f2bf(pv[t][r]);
            asm volatile("s_waitcnt lgkmcnt(0)" ::: "memory");
            short8 pf = *(const short8*)&Ps[w][lm][quad * 8];

            // ---- O += P V ----
#pragma unroll
            for (int nt = 0; nt < 16; nt++) {
                short8 vf = *(const short8*)&Vt[nt * 16 + lm][quad * 8];
                o_acc[nt] = mfma16(pf, vf, o_acc[nt]);
            }
        }
        __syncthreads();
    }

    // ---- epilogue: normalize and store to ATT (b, s, h*HD+d) ----
    const int row0 = q0 + w * 16 + quad * 4;
#pragma unroll
    for (int r = 0; r < 4; r++) {
        float inv = 1.0f / l_r[r];
        unsigned short* Ob = O + ((size_t)b * SS + row0 + r) * NQ + h * HDD;
#pragma unroll
        for (int nt = 0; nt < 16; nt++)
            Ob[nt * 16 + lm] = f2bf(o_acc[nt][r] * inv);
    }
}

// ---------------------------------------------------------------------------
extern "C" void kernel_launch(void* const* d_in, const int* in_sizes, int n_in,
                              void* d_out, int out_size, void* d_ws, size_t ws_size,
                              hipStream_t stream)
{
    const float* x    = (const float*)d_in[0];
    const float* cosb = (const float*)d_in[1];
    const float* sinb = (const float*)d_in[2];
    // d_in[3] = mask (pure causal + NEG, reimplemented in-kernel)
    const float* q_w  = (const float*)d_in[4];
    const float* k_w  = (const float*)d_in[5];
    const float* v_w  = (const float*)d_in[6];
    const float* o_w  = (const float*)d_in[7];
    const float* qn_w = (const float*)d_in[8];
    const float* kn_w = (const float*)d_in[9];
    float* out = (float*)d_out;

    unsigned short* Q   = (unsigned short*)d_ws;            // 4096x2048 bf16 (16 MB)
    unsigned short* K   = Q + (size_t)MM * NQ;              // 4096x1024 (8 MB)
    unsigned short* V   = K + (size_t)MM * NKV;             // 4096x1024 (8 MB)
    unsigned short* ATT = V + (size_t)MM * NKV;             // 4096x2048 (16 MB)

    // QKV projections (A = x as (4096,2560) fp32, weights (N,K) fp32 = B^T form)
    gemm_bt<<<dim3(MM / 128, NQ  / 128), 256, 0, stream>>>(x, q_w, Q, MM, NQ,  DD);
    gemm_bt<<<dim3(MM / 128, NKV / 128), 256, 0, stream>>>(x, k_w, K, MM, NKV, DD);
    gemm_bt<<<dim3(MM / 128, NKV / 128), 256, 0, stream>>>(x, v_w, V, MM, NKV, DD);

    // RMSNorm + RoPE on Q and K (per (b,s,h) row of 256)
    norm_rope<<<dim3(MM, HH),   256, 0, stream>>>(Q, qn_w, cosb, sinb, HH);
    norm_rope<<<dim3(MM, HKVV), 256, 0, stream>>>(K, kn_w, cosb, sinb, HKVV);

    // Causal softcapped GQA attention
    attn_kernel<<<dim3(SS / TQ, HH, BB), 256, 0, stream>>>(Q, K, V, ATT);

    // Output projection: out fp32 = ATT(bf16) @ o_w(fp32)^T
    gemm_bt<<<dim3(MM / 128, DD / 128), 256, 0, stream>>>(ATT, o_w, out, MM, DD, NQ);
}

// Round 3
// 1058.458 us; speedup vs baseline: 1.1940x; 1.1940x over previous
//
#include <hip/hip_runtime.h>
#include <hip/hip_bf16.h>

// Problem constants
#define BB   2
#define SS   2048
#define DD   2560
#define HH   8
#define HKVV 4
#define HDD  256
#define MM   (BB*SS)      // 4096 rows
#define NQ   (HH*HDD)     // 2048
#define NKV  (HKVV*HDD)   // 1024
#define SCALING 0.0625f   // 256^-0.5
#define SOFTCAP 4096.0f

typedef __attribute__((ext_vector_type(8))) short short8;       // 8 bf16 (4 VGPR)
typedef __attribute__((ext_vector_type(8))) unsigned short ushort8;
typedef __attribute__((ext_vector_type(4))) unsigned short us4;
typedef __attribute__((ext_vector_type(4))) float f32x4;        // MFMA C/D

__device__ __forceinline__ float bf2f(unsigned short u) {
    union { unsigned int i; float f; } v; v.i = ((unsigned int)u) << 16; return v.f;
}
__device__ __forceinline__ unsigned short f2bf(float f) {
    union { float f; unsigned int i; } v; v.f = f;
    return (unsigned short)((v.i + 0x7fffu + ((v.i >> 16) & 1u)) >> 16);
}
__device__ __forceinline__ f32x4 mfma16(short8 a, short8 b, f32x4 c) {
    return __builtin_amdgcn_mfma_f32_16x16x32_bf16(a, b, c, 0, 0, 0);
}

// dtype-polymorphic 8-element load (→ bf16x8) and scalar store
__device__ __forceinline__ ushort8 ld8(const unsigned short* p) { return *(const ushort8*)p; }
__device__ __forceinline__ ushort8 ld8(const float* p) {
    ushort8 r;
#pragma unroll
    for (int i = 0; i < 8; i++) r[i] = f2bf(p[i]);
    return r;
}
__device__ __forceinline__ void stc(float* p, float v)          { *p = v; }
__device__ __forceinline__ void stc(unsigned short* p, float v) { *p = f2bf(v); }

// fast softcap: SOFTCAP * tanh(x/SOFTCAP), x pre-scaled
__device__ __forceinline__ float softcap(float s) {
    float x2 = s * (2.0f / SOFTCAP);
    x2 = fminf(fmaxf(x2, -20.0f), 20.0f);
    float ex = __expf(x2);
    return SOFTCAP * (ex - 1.0f) / (ex + 1.0f);
}

// ---------------------------------------------------------------------------
// C(M,N) = A(M,K) @ B(N,K)^T. A/B converted to bf16 in LDS staging, fp32
// accum. 128x128 tile, 4 waves, each wave 64x64 = 4x4 MFMA tiles, BK=32.
// ---------------------------------------------------------------------------
template<typename TA, typename TB, typename TC>
__global__ __launch_bounds__(256) void gemm_bt(const TA* __restrict__ A,
                                               const TB* __restrict__ Bm,
                                               TC* __restrict__ C,
                                               int M, int N, int K)
{
    __shared__ __align__(16) unsigned short As[128][40];
    __shared__ __align__(16) unsigned short Bs[128][40];

    const int tid  = threadIdx.x;
    const int bm   = blockIdx.x, bn = blockIdx.y;
    const int wave = tid >> 6, lane = tid & 63;
    const int quad = lane >> 4, lm = lane & 15;
    const int wm = (wave >> 1) * 64, wn = (wave & 1) * 64;

    f32x4 acc[4][4];
#pragma unroll
    for (int i = 0; i < 4; i++)
#pragma unroll
        for (int j = 0; j < 4; j++) acc[i][j] = (f32x4)0.0f;

    const int srow = tid >> 2;           // 0..63
    const int sch  = (tid & 3) * 8;      // 0,8,16,24
    const TA* Ab = A  + (size_t)(bm * 128) * K;
    const TB* Bb = Bm + (size_t)(bn * 128) * K;

    for (int k0 = 0; k0 < K; k0 += 32) {
        *(ushort8*)&As[srow     ][sch] = ld8(&Ab[(size_t)(srow     ) * K + k0 + sch]);
        *(ushort8*)&As[srow + 64][sch] = ld8(&Ab[(size_t)(srow + 64) * K + k0 + sch]);
        *(ushort8*)&Bs[srow     ][sch] = ld8(&Bb[(size_t)(srow     ) * K + k0 + sch]);
        *(ushort8*)&Bs[srow + 64][sch] = ld8(&Bb[(size_t)(srow + 64) * K + k0 + sch]);
        __syncthreads();

        short8 af[4], bf[4];
#pragma unroll
        for (int t = 0; t < 4; t++) af[t] = *(const short8*)&As[wm + t * 16 + lm][quad * 8];
#pragma unroll
        for (int t = 0; t < 4; t++) bf[t] = *(const short8*)&Bs[wn + t * 16 + lm][quad * 8];
#pragma unroll
        for (int i = 0; i < 4; i++)
#pragma unroll
            for (int j = 0; j < 4; j++)
                acc[i][j] = mfma16(af[i], bf[j], acc[i][j]);
        __syncthreads();
    }

    // C/D layout: row = quad*4 + r, col = lm  [verified m89/m91]
#pragma unroll
    for (int i = 0; i < 4; i++)
#pragma unroll
        for (int j = 0; j < 4; j++)
#pragma unroll
            for (int r = 0; r < 4; r++) {
                int row = bm * 128 + wm + i * 16 + quad * 4 + r;
                int col = bn * 128 + wn + j * 16 + lm;
                stc(&C[(size_t)row * N + col], acc[i][j][r]);
            }
}

// ---------------------------------------------------------------------------
// Same GEMM, but epilogue writes V^T: C row=(b,s), col=(kvh,d) stored to
// VT(b, kvh, d, s) as packed ushort4 along s (r=0..3 are consecutive rows).
// ---------------------------------------------------------------------------
template<typename TA, typename TB>
__global__ __launch_bounds__(256) void gemm_bt_vt(const TA* __restrict__ A,
                                                  const TB* __restrict__ Bm,
                                                  unsigned short* __restrict__ VT,
                                                  int M, int N, int K)
{
    __shared__ __align__(16) unsigned short As[128][40];
    __shared__ __align__(16) unsigned short Bs[128][40];

    const int tid  = threadIdx.x;
    const int bm   = blockIdx.x, bn = blockIdx.y;
    const int wave = tid >> 6, lane = tid & 63;
    const int quad = lane >> 4, lm = lane & 15;
    const int wm = (wave >> 1) * 64, wn = (wave & 1) * 64;

    f32x4 acc[4][4];
#pragma unroll
    for (int i = 0; i < 4; i++)
#pragma unroll
        for (int j = 0; j < 4; j++) acc[i][j] = (f32x4)0.0f;

    const int srow = tid >> 2;
    const int sch  = (tid & 3) * 8;
    const TA* Ab = A  + (size_t)(bm * 128) * K;
    const TB* Bb = Bm + (size_t)(bn * 128) * K;

    for (int k0 = 0; k0 < K; k0 += 32) {
        *(ushort8*)&As[srow     ][sch] = ld8(&Ab[(size_t)(srow     ) * K + k0 + sch]);
        *(ushort8*)&As[srow + 64][sch] = ld8(&Ab[(size_t)(srow + 64) * K + k0 + sch]);
        *(ushort8*)&Bs[srow     ][sch] = ld8(&Bb[(size_t)(srow     ) * K + k0 + sch]);
        *(ushort8*)&Bs[srow + 64][sch] = ld8(&Bb[(size_t)(srow + 64) * K + k0 + sch]);
        __syncthreads();

        short8 af[4], bf[4];
#pragma unroll
        for (int t = 0; t < 4; t++) af[t] = *(const short8*)&As[wm + t * 16 + lm][quad * 8];
#pragma unroll
        for (int t = 0; t < 4; t++) bf[t] = *(const short8*)&Bs[wn + t * 16 + lm][quad * 8];
#pragma unroll
        for (int i = 0; i < 4; i++)
#pragma unroll
            for (int j = 0; j < 4; j++)
                acc[i][j] = mfma16(af[i], bf[j], acc[i][j]);
        __syncthreads();
    }

#pragma unroll
    for (int i = 0; i < 4; i++)
#pragma unroll
        for (int j = 0; j < 4; j++) {
            int row0 = bm * 128 + wm + i * 16 + quad * 4;   // b*SS + s0
            int col  = bn * 128 + wn + j * 16 + lm;         // kvh*HDD + d
            int b    = row0 >> 11, s0 = row0 & (SS - 1);
            int kvh  = col >> 8,   d  = col & (HDD - 1);
            us4 pk;
#pragma unroll
            for (int r = 0; r < 4; r++) pk[r] = f2bf(acc[i][j][r]);
            *(us4*)&VT[(((size_t)b * HKVV + kvh) * HDD + d) * SS + s0] = pk;
        }
}

// ---------------------------------------------------------------------------
// Fused RMSNorm + RoPE in place on bf16 X laid out (b, s, h, d), one block
// per (bs, h) row of HD=256. cos/sin/nw are fp32.
// ---------------------------------------------------------------------------
__global__ __launch_bounds__(256) void norm_rope(unsigned short* __restrict__ X,
                                                 const float* __restrict__ nw,
                                                 const float* __restrict__ cosb,
                                                 const float* __restrict__ sinb,
                                                 int nheads)
{
    const int bs = blockIdx.x;
    const int h  = blockIdx.y;
    const int t  = threadIdx.x;

    __shared__ float xs[256];
    __shared__ float red[4];

    const size_t base = ((size_t)bs * nheads + h) * HDD;
    float v = bf2f(X[base + t]);
    xs[t] = v;

    float p = v * v;
#pragma unroll
    for (int off = 32; off >= 1; off >>= 1) p += __shfl_xor(p, off);
    if ((t & 63) == 0) red[t >> 6] = p;
    __syncthreads();
    float sum = red[0] + red[1] + red[2] + red[3];
    float rs  = rsqrtf(sum * (1.0f / HDD) + 1e-6f);

    const int pt = (t + 128) & 255;
    float w1 = 1.0f + nw[t];
    float w2 = 1.0f + nw[pt];
    float normed  = v * rs * w1;
    float partner = xs[pt] * rs * w2;
    float rot = (t < 128) ? -partner : partner;   // rotate_half: [-x2, x1]
    float c = cosb[(size_t)bs * HDD + t];
    float s = sinb[(size_t)bs * HDD + t];
    X[base + t] = f2bf(normed * c + rot * s);
}

// ---------------------------------------------------------------------------
// Per-wave flash attention, causal, GQA, softcap. Zero block barriers.
// Each wave owns 16 q-rows; K and V^T fragments read directly from global
// (L2-resident, heavily reused). Tile index permuted (*37 mod 128) so heavy
// (large q0) and light waves mix on each CU — causal load balance.
// Q,K ws layout (b,s,h,d) bf16; VT (b,kvh,d,s) bf16; ATT (b,s,h*HD+d) bf16.
// ---------------------------------------------------------------------------
__global__ __launch_bounds__(256) void attn_kernel(const unsigned short* __restrict__ Q,
                                                   const unsigned short* __restrict__ K,
                                                   const unsigned short* __restrict__ VT,
                                                   unsigned short* __restrict__ O)
{
    const int tid = threadIdx.x, w = tid >> 6, lane = tid & 63;
    const int quad = lane >> 4, lm = lane & 15;
    const int h = blockIdx.y, b = blockIdx.z, kvh = h >> 1;

    const int gw    = blockIdx.x * 4 + w;        // 0..127
    const int qt    = (gw * 37) & 127;           // bijective permutation
    const int qrow0 = qt * 16;

    __shared__ __align__(16) unsigned short Ps[4][16][32];  // per-wave P round-trip

    // Q A-fragments: lane holds Q[m=lm][k=quad*8+j] per 32-wide chunk c
    const unsigned short* Qb = Q + (((size_t)b * SS + qrow0 + lm) * HH + h) * HDD;
    short8 qf[8];
#pragma unroll
    for (int c = 0; c < 8; c++) qf[c] = *(const short8*)&Qb[c * 32 + quad * 8];

    const unsigned short* Kb = K  + (size_t)b * SS * NKV + (size_t)kvh * HDD;       // row s, stride NKV
    const unsigned short* Vb = VT + ((size_t)b * HKVV + kvh) * HDD * (size_t)SS;    // row d, stride SS

    f32x4 o_acc[16];
#pragma unroll
    for (int i = 0; i < 16; i++) o_acc[i] = (f32x4)0.0f;
    float m_r[4], l_r[4];
#pragma unroll
    for (int r = 0; r < 4; r++) { m_r[r] = -1e30f; l_r[r] = 0.0f; }

    const int row_base = qrow0 + quad * 4;
    const int nsteps   = (qt + 2) >> 1;          // ceil((qrow0+16)/32)

    for (int st = 0; st < nsteps; st++) {
        const int k0 = st * 32;

        // ---- S = Q K^T (16 x 32), K frags direct from global ----
        f32x4 sa[2];
        sa[0] = (f32x4)0.0f; sa[1] = (f32x4)0.0f;
#pragma unroll
        for (int c = 0; c < 8; c++) {
            short8 kf0 = *(const short8*)&Kb[(size_t)(k0      + lm) * NKV + c * 32 + quad * 8];
            short8 kf1 = *(const short8*)&Kb[(size_t)(k0 + 16 + lm) * NKV + c * 32 + quad * 8];
            sa[0] = mfma16(qf[c], kf0, sa[0]);
            sa[1] = mfma16(qf[c], kf1, sa[1]);
        }

        // ---- scale, softcap, causal mask, online softmax ----
        const bool need_mask = (k0 + 31 > qrow0);
        float pv[2][4], mt[4];
#pragma unroll
        for (int r = 0; r < 4; r++) mt[r] = -1e30f;
#pragma unroll
        for (int t = 0; t < 2; t++) {
            int key = k0 + t * 16 + lm;
#pragma unroll
            for (int r = 0; r < 4; r++) {
                float s = softcap(sa[t][r] * SCALING);
                if (need_mask && key > row_base + r) s = -1e30f;
                pv[t][r] = s;
                mt[r] = fmaxf(mt[r], s);
            }
        }
#pragma unroll
        for (int off = 1; off < 16; off <<= 1)
#pragma unroll
            for (int r = 0; r < 4; r++) mt[r] = fmaxf(mt[r], __shfl_xor(mt[r], off));

        float alpha[4];
#pragma unroll
        for (int r = 0; r < 4; r++) {
            float mn = fmaxf(m_r[r], mt[r]);
            alpha[r] = __expf(m_r[r] - mn);
            m_r[r] = mn;
        }
        float sums[4] = {0.f, 0.f, 0.f, 0.f};
#pragma unroll
        for (int t = 0; t < 2; t++)
#pragma unroll
            for (int r = 0; r < 4; r++) {
                float e = __expf(pv[t][r] - m_r[r]);
                pv[t][r] = e;
                sums[r] += e;
            }
#pragma unroll
        for (int off = 1; off < 16; off <<= 1)
#pragma unroll
            for (int r = 0; r < 4; r++) sums[r] += __shfl_xor(sums[r], off);
#pragma unroll
        for (int r = 0; r < 4; r++) l_r[r] = l_r[r] * alpha[r] + sums[r];
#pragma unroll
        for (int i = 0; i < 16; i++)
#pragma unroll
            for (int r = 0; r < 4; r++) o_acc[i][r] *= alpha[r];

        // ---- P: C layout -> A layout via per-wave LDS (no barrier) ----
#pragma unroll
        for (int t = 0; t < 2; t++)
#pragma unroll
            for (int r = 0; r < 4; r++)
                Ps[w][quad * 4 + r][t * 16 + lm] = f2bf(pv[t][r]);
        asm volatile("s_waitcnt lgkmcnt(0)" ::: "memory");
        short8 pf = *(const short8*)&Ps[w][lm][quad * 8];

        // ---- O += P V, V^T frags direct from global ----
#pragma unroll
        for (int nt = 0; nt < 16; nt++) {
            short8 vf = *(const short8*)&Vb[(size_t)(nt * 16 + lm) * SS + k0 + quad * 8];
            o_acc[nt] = mfma16(pf, vf, o_acc[nt]);
        }
    }

    // ---- epilogue: normalize, store ATT (b, s, h*HD+d) ----
#pragma unroll
    for (int r = 0; r < 4; r++) {
        float inv = 1.0f / l_r[r];
        unsigned short* Ob = O + ((size_t)b * SS + row_base + r) * NQ + h * HDD;
#pragma unroll
        for (int nt = 0; nt < 16; nt++)
            Ob[nt * 16 + lm] = f2bf(o_acc[nt][r] * inv);
    }
}

// ---------------------------------------------------------------------------
extern "C" void kernel_launch(void* const* d_in, const int* in_sizes, int n_in,
                              void* d_out, int out_size, void* d_ws, size_t ws_size,
                              hipStream_t stream)
{
    const float* x    = (const float*)d_in[0];
    const float* cosb = (const float*)d_in[1];
    const float* sinb = (const float*)d_in[2];
    // d_in[3] = mask (pure causal + NEG, reimplemented in-kernel)
    const float* q_w  = (const float*)d_in[4];
    const float* k_w  = (const float*)d_in[5];
    const float* v_w  = (const float*)d_in[6];
    const float* o_w  = (const float*)d_in[7];
    const float* qn_w = (const float*)d_in[8];
    const float* kn_w = (const float*)d_in[9];
    float* out = (float*)d_out;

    unsigned short* Q   = (unsigned short*)d_ws;            // 4096x2048 bf16 (16.8 MB)
    unsigned short* K   = Q + (size_t)MM * NQ;              // 4096x1024 (8.4 MB)
    unsigned short* VT  = K + (size_t)MM * NKV;             // (b,kvh,d,s) (8.4 MB)
    unsigned short* ATT = VT + (size_t)MM * NKV;            // 4096x2048 (16.8 MB)

    // QKV projections (A = x (4096,2560) fp32, weights (N,K) fp32 = B^T form)
    gemm_bt   <<<dim3(MM / 128, NQ  / 128), 256, 0, stream>>>(x, q_w, Q,  MM, NQ,  DD);
    gemm_bt   <<<dim3(MM / 128, NKV / 128), 256, 0, stream>>>(x, k_w, K,  MM, NKV, DD);
    gemm_bt_vt<<<dim3(MM / 128, NKV / 128), 256, 0, stream>>>(x, v_w, VT, MM, NKV, DD);

    // RMSNorm + RoPE on Q and K (per (b,s,h) row of 256)
    norm_rope<<<dim3(MM, HH),   256, 0, stream>>>(Q, qn_w, cosb, sinb, HH);
    norm_rope<<<dim3(MM, HKVV), 256, 0, stream>>>(K, kn_w, cosb, sinb, HKVV);

    // Causal softcapped GQA attention (per-wave, barrier-free)
    attn_kernel<<<dim3(SS / 16 / 4, HH, BB), 256, 0, stream>>>(Q, K, VT, ATT);

    // Output projection: out fp32 = ATT(bf16) @ o_w(fp32)^T
    gemm_bt<<<dim3(MM / 128, DD / 128), 256, 0, stream>>>(ATT, o_w, out, MM, DD, NQ);
}

// Round 4
// 693.512 us; speedup vs baseline: 1.8224x; 1.5262x over previous
//
#include <hip/hip_runtime.h>
#include <hip/hip_bf16.h>

// Problem constants
#define BB   2
#define SS   2048
#define DD   2560
#define HH   8
#define HKVV 4
#define HDD  256
#define MM   (BB*SS)      // 4096 rows
#define NQ   (HH*HDD)     // 2048
#define NKV  (HKVV*HDD)   // 1024
#define SCALING 0.0625f   // 256^-0.5
#define SOFTCAP 4096.0f
#define CAPC    (1.0f/(3.0f*SOFTCAP*SOFTCAP))  // cubic softcap coefficient
#define M0      20.0f     // fixed softmax max: |scores| <= 16.2 by Cauchy-Schwarz

typedef __attribute__((ext_vector_type(8))) short short8;       // 8 bf16 (4 VGPR)
typedef __attribute__((ext_vector_type(8))) unsigned short ushort8;
typedef __attribute__((ext_vector_type(4))) unsigned short us4;
typedef __attribute__((ext_vector_type(4))) float f32x4;        // MFMA C/D

__device__ __forceinline__ float bf2f(unsigned short u) {
    union { unsigned int i; float f; } v; v.i = ((unsigned int)u) << 16; return v.f;
}
__device__ __forceinline__ unsigned short f2bf(float f) {
    union { float f; unsigned int i; } v; v.f = f;
    return (unsigned short)((v.i + 0x7fffu + ((v.i >> 16) & 1u)) >> 16);
}
__device__ __forceinline__ f32x4 mfma16(short8 a, short8 b, f32x4 c) {
    return __builtin_amdgcn_mfma_f32_16x16x32_bf16(a, b, c, 0, 0, 0);
}

// async global->LDS, 16B per lane (gfx950)
__device__ __forceinline__ void async_cp16(const void* g, void* l) {
    __builtin_amdgcn_global_load_lds(
        (__attribute__((address_space(1))) void*)(g),
        (__attribute__((address_space(3))) void*)(l), 16, 0, 0);
}

// dtype-polymorphic 8-element load (-> bf16x8) and scalar store (fallback GEMM)
__device__ __forceinline__ ushort8 ld8(const unsigned short* p) { return *(const ushort8*)p; }
__device__ __forceinline__ ushort8 ld8(const float* p) {
    ushort8 r;
#pragma unroll
    for (int i = 0; i < 8; i++) r[i] = f2bf(p[i]);
    return r;
}
__device__ __forceinline__ void stc(float* p, float v)          { *p = v; }
__device__ __forceinline__ void stc(unsigned short* p, float v) { *p = f2bf(v); }

// ---------------------------------------------------------------------------
// fp32 -> bf16 bulk convert (RNE), float4-vectorized grid-stride
// ---------------------------------------------------------------------------
__global__ __launch_bounds__(256) void cvt_bf16(const float* __restrict__ in,
                                                unsigned short* __restrict__ out, int n4)
{
    int i = blockIdx.x * 256 + threadIdx.x;
    const int stride = gridDim.x * 256;
    for (; i < n4; i += stride) {
        float4 v = ((const float4*)in)[i];
        us4 o;
        o[0] = f2bf(v.x); o[1] = f2bf(v.y); o[2] = f2bf(v.z); o[3] = f2bf(v.w);
        ((us4*)out)[i] = o;
    }
}

// ---------------------------------------------------------------------------
// m97-style GEMM: C(M,N) = A(M,K) @ B(N,K)^T, A/B bf16 in HBM, staged via
// global_load_lds(16B) into unpadded [128][32] LDS. 128x128 tile, 4 waves.
// VT_OUT: epilogue writes V^T (b,kvh,d,s) instead of row-major C.
// ---------------------------------------------------------------------------
template<typename TC, bool VT_OUT>
__global__ __launch_bounds__(256) void gemm_bt16(const unsigned short* __restrict__ A,
                                                 const unsigned short* __restrict__ Bm,
                                                 TC* __restrict__ C,
                                                 int M, int N, int K)
{
    __shared__ __align__(16) unsigned short As[128][32];
    __shared__ __align__(16) unsigned short Bs[128][32];

    const int tid  = threadIdx.x;
    const int bm   = blockIdx.x, bn = blockIdx.y;
    const int wave = tid >> 6, lane = tid & 63;
    const int quad = lane >> 4, lm = lane & 15;
    const int wm = (wave >> 1) * 64, wn = (wave & 1) * 64;

    f32x4 acc[4][4];
#pragma unroll
    for (int i = 0; i < 4; i++)
#pragma unroll
        for (int j = 0; j < 4; j++) acc[i][j] = (f32x4)0.0f;

    unsigned short* AsF = &As[0][0];
    unsigned short* BsF = &Bs[0][0];
    const int grow = tid >> 2;           // 0..63
    const int gcol = (tid & 3) * 8;      // 0,8,16,24
    const unsigned short* Ab = A  + (size_t)(bm * 128) * K;
    const unsigned short* Bb = Bm + (size_t)(bn * 128) * K;

    for (int k0 = 0; k0 < K; k0 += 32) {
        async_cp16(&Ab[(size_t)(grow     ) * K + k0 + gcol], AsF + tid * 8);
        async_cp16(&Ab[(size_t)(grow + 64) * K + k0 + gcol], AsF + 2048 + tid * 8);
        async_cp16(&Bb[(size_t)(grow     ) * K + k0 + gcol], BsF + tid * 8);
        async_cp16(&Bb[(size_t)(grow + 64) * K + k0 + gcol], BsF + 2048 + tid * 8);
        __syncthreads();   // compiler drains vmcnt before barrier -> LDS valid

        short8 af[4], bf[4];
#pragma unroll
        for (int t = 0; t < 4; t++) af[t] = *(const short8*)&As[wm + t * 16 + lm][quad * 8];
#pragma unroll
        for (int t = 0; t < 4; t++) bf[t] = *(const short8*)&Bs[wn + t * 16 + lm][quad * 8];
#pragma unroll
        for (int i = 0; i < 4; i++)
#pragma unroll
            for (int j = 0; j < 4; j++)
                acc[i][j] = mfma16(af[i], bf[j], acc[i][j]);
        __syncthreads();
    }

    // C/D layout: row = quad*4 + r, col = lm  [verified m89/m91]
#pragma unroll
    for (int i = 0; i < 4; i++)
#pragma unroll
        for (int j = 0; j < 4; j++) {
            if constexpr (VT_OUT) {
                int row0 = bm * 128 + wm + i * 16 + quad * 4;   // b*SS + s0
                int col  = bn * 128 + wn + j * 16 + lm;         // kvh*HDD + d
                int b    = row0 >> 11, s0 = row0 & (SS - 1);
                int kvh  = col >> 8,   d  = col & (HDD - 1);
                us4 pk;
#pragma unroll
                for (int r = 0; r < 4; r++) pk[r] = f2bf(acc[i][j][r]);
                *(us4*)&C[(((size_t)b * HKVV + kvh) * HDD + d) * SS + s0] = pk;
            } else {
#pragma unroll
                for (int r = 0; r < 4; r++) {
                    int row = bm * 128 + wm + i * 16 + quad * 4 + r;
                    int col = bn * 128 + wn + j * 16 + lm;
                    stc(&C[(size_t)row * N + col], acc[i][j][r]);
                }
            }
        }
}

// ---------------------------------------------------------------------------
// Fallback GEMM (fp32/bf16 operands staged with in-reg convert) — round-3 ver.
// ---------------------------------------------------------------------------
template<typename TA, typename TB, typename TC>
__global__ __launch_bounds__(256) void gemm_bt(const TA* __restrict__ A,
                                               const TB* __restrict__ Bm,
                                               TC* __restrict__ C,
                                               int M, int N, int K)
{
    __shared__ __align__(16) unsigned short As[128][40];
    __shared__ __align__(16) unsigned short Bs[128][40];

    const int tid  = threadIdx.x;
    const int bm   = blockIdx.x, bn = blockIdx.y;
    const int wave = tid >> 6, lane = tid & 63;
    const int quad = lane >> 4, lm = lane & 15;
    const int wm = (wave >> 1) * 64, wn = (wave & 1) * 64;

    f32x4 acc[4][4];
#pragma unroll
    for (int i = 0; i < 4; i++)
#pragma unroll
        for (int j = 0; j < 4; j++) acc[i][j] = (f32x4)0.0f;

    const int srow = tid >> 2;
    const int sch  = (tid & 3) * 8;
    const TA* Ab = A  + (size_t)(bm * 128) * K;
    const TB* Bb = Bm + (size_t)(bn * 128) * K;

    for (int k0 = 0; k0 < K; k0 += 32) {
        *(ushort8*)&As[srow     ][sch] = ld8(&Ab[(size_t)(srow     ) * K + k0 + sch]);
        *(ushort8*)&As[srow + 64][sch] = ld8(&Ab[(size_t)(srow + 64) * K + k0 + sch]);
        *(ushort8*)&Bs[srow     ][sch] = ld8(&Bb[(size_t)(srow     ) * K + k0 + sch]);
        *(ushort8*)&Bs[srow + 64][sch] = ld8(&Bb[(size_t)(srow + 64) * K + k0 + sch]);
        __syncthreads();

        short8 af[4], bf[4];
#pragma unroll
        for (int t = 0; t < 4; t++) af[t] = *(const short8*)&As[wm + t * 16 + lm][quad * 8];
#pragma unroll
        for (int t = 0; t < 4; t++) bf[t] = *(const short8*)&Bs[wn + t * 16 + lm][quad * 8];
#pragma unroll
        for (int i = 0; i < 4; i++)
#pragma unroll
            for (int j = 0; j < 4; j++)
                acc[i][j] = mfma16(af[i], bf[j], acc[i][j]);
        __syncthreads();
    }

#pragma unroll
    for (int i = 0; i < 4; i++)
#pragma unroll
        for (int j = 0; j < 4; j++)
#pragma unroll
            for (int r = 0; r < 4; r++) {
                int row = bm * 128 + wm + i * 16 + quad * 4 + r;
                int col = bn * 128 + wn + j * 16 + lm;
                stc(&C[(size_t)row * N + col], acc[i][j][r]);
            }
}

template<typename TA, typename TB>
__global__ __launch_bounds__(256) void gemm_bt_vt(const TA* __restrict__ A,
                                                  const TB* __restrict__ Bm,
                                                  unsigned short* __restrict__ VT,
                                                  int M, int N, int K)
{
    __shared__ __align__(16) unsigned short As[128][40];
    __shared__ __align__(16) unsigned short Bs[128][40];

    const int tid  = threadIdx.x;
    const int bm   = blockIdx.x, bn = blockIdx.y;
    const int wave = tid >> 6, lane = tid & 63;
    const int quad = lane >> 4, lm = lane & 15;
    const int wm = (wave >> 1) * 64, wn = (wave & 1) * 64;

    f32x4 acc[4][4];
#pragma unroll
    for (int i = 0; i < 4; i++)
#pragma unroll
        for (int j = 0; j < 4; j++) acc[i][j] = (f32x4)0.0f;

    const int srow = tid >> 2;
    const int sch  = (tid & 3) * 8;
    const TA* Ab = A  + (size_t)(bm * 128) * K;
    const TB* Bb = Bm + (size_t)(bn * 128) * K;

    for (int k0 = 0; k0 < K; k0 += 32) {
        *(ushort8*)&As[srow     ][sch] = ld8(&Ab[(size_t)(srow     ) * K + k0 + sch]);
        *(ushort8*)&As[srow + 64][sch] = ld8(&Ab[(size_t)(srow + 64) * K + k0 + sch]);
        *(ushort8*)&Bs[srow     ][sch] = ld8(&Bb[(size_t)(srow     ) * K + k0 + sch]);
        *(ushort8*)&Bs[srow + 64][sch] = ld8(&Bb[(size_t)(srow + 64) * K + k0 + sch]);
        __syncthreads();

        short8 af[4], bf[4];
#pragma unroll
        for (int t = 0; t < 4; t++) af[t] = *(const short8*)&As[wm + t * 16 + lm][quad * 8];
#pragma unroll
        for (int t = 0; t < 4; t++) bf[t] = *(const short8*)&Bs[wn + t * 16 + lm][quad * 8];
#pragma unroll
        for (int i = 0; i < 4; i++)
#pragma unroll
            for (int j = 0; j < 4; j++)
                acc[i][j] = mfma16(af[i], bf[j], acc[i][j]);
        __syncthreads();
    }

#pragma unroll
    for (int i = 0; i < 4; i++)
#pragma unroll
        for (int j = 0; j < 4; j++) {
            int row0 = bm * 128 + wm + i * 16 + quad * 4;
            int col  = bn * 128 + wn + j * 16 + lm;
            int b    = row0 >> 11, s0 = row0 & (SS - 1);
            int kvh  = col >> 8,   d  = col & (HDD - 1);
            us4 pk;
#pragma unroll
            for (int r = 0; r < 4; r++) pk[r] = f2bf(acc[i][j][r]);
            *(us4*)&VT[(((size_t)b * HKVV + kvh) * HDD + d) * SS + s0] = pk;
        }
}

// ---------------------------------------------------------------------------
// Fused RMSNorm + RoPE in place on bf16 X (b, s, h, d), one block per (bs,h).
// ---------------------------------------------------------------------------
__global__ __launch_bounds__(256) void norm_rope(unsigned short* __restrict__ X,
                                                 const float* __restrict__ nw,
                                                 const float* __restrict__ cosb,
                                                 const float* __restrict__ sinb,
                                                 int nheads)
{
    const int bs = blockIdx.x;
    const int h  = blockIdx.y;
    const int t  = threadIdx.x;

    __shared__ float xs[256];
    __shared__ float red[4];

    const size_t base = ((size_t)bs * nheads + h) * HDD;
    float v = bf2f(X[base + t]);
    xs[t] = v;

    float p = v * v;
#pragma unroll
    for (int off = 32; off >= 1; off >>= 1) p += __shfl_xor(p, off);
    if ((t & 63) == 0) red[t >> 6] = p;
    __syncthreads();
    float sum = red[0] + red[1] + red[2] + red[3];
    float rs  = rsqrtf(sum * (1.0f / HDD) + 1e-6f);

    const int pt = (t + 128) & 255;
    float w1 = 1.0f + nw[t];
    float w2 = 1.0f + nw[pt];
    float normed  = v * rs * w1;
    float partner = xs[pt] * rs * w2;
    float rot = (t < 128) ? -partner : partner;   // rotate_half: [-x2, x1]
    float c = cosb[(size_t)bs * HDD + t];
    float s = sinb[(size_t)bs * HDD + t];
    X[base + t] = f2bf(normed * c + rot * s);
}

// ---------------------------------------------------------------------------
// Per-wave flash attention, causal, GQA, cubic softcap, FIXED-max softmax
// (|scores| <= 16.2 by Cauchy-Schwarz: unit-RMS q,k of dim 256, x1/16 scale).
// Each wave handles the balanced pair (qt, 127-qt) of 16-row q-tiles -> all
// 1024 waves do ~65 k-steps. No block barriers, no cross-lane in k-loop.
// K frags prefetched one tile ahead; V frags prefetched across softmax.
// ---------------------------------------------------------------------------
__global__ __launch_bounds__(256) void attn_kernel(const unsigned short* __restrict__ Q,
                                                   const unsigned short* __restrict__ K,
                                                   const unsigned short* __restrict__ VT,
                                                   unsigned short* __restrict__ O)
{
    const int tid = threadIdx.x, w = tid >> 6, lane = tid & 63;
    const int quad = lane >> 4, lm = lane & 15;
    const int h = blockIdx.y, b = blockIdx.z, kvh = h >> 1;
    const int p = blockIdx.x * 4 + w;            // 0..63

    __shared__ __align__(16) unsigned short Ps[4][16][32];  // per-wave P round-trip

    const unsigned short* Kb = K  + (size_t)b * SS * NKV + (size_t)kvh * HDD;    // row s, stride NKV
    const unsigned short* Vb = VT + ((size_t)b * HKVV + kvh) * HDD * (size_t)SS; // row d, stride SS

    for (int ph = 0; ph < 2; ph++) {
        const int qt    = ph ? (127 - p) : p;
        const int qrow0 = qt * 16;
        const int T     = (qt + 2) >> 1;         // k-tiles of 32 keys
        const int row   = qrow0 + quad * 4;      // + r

        // Q A-fragments: lane holds Q[m=lm][k=quad*8+j] per 32-wide chunk c
        const unsigned short* Qb = Q + (((size_t)b * SS + qrow0 + lm) * HH + h) * HDD;
        short8 qf[8];
#pragma unroll
        for (int c = 0; c < 8; c++) qf[c] = *(const short8*)&Qb[c * 32 + quad * 8];

        f32x4 o_acc[16];
#pragma unroll
        for (int i = 0; i < 16; i++) o_acc[i] = (f32x4)0.0f;
        float l_r[4] = {0.f, 0.f, 0.f, 0.f};

        // prologue: load tile 0 K and V frags
        short8 kf[16], vf[16];
        {
            const unsigned short* kp = Kb + (size_t)lm * NKV;
#pragma unroll
            for (int c = 0; c < 8; c++) {
                kf[c]     = *(const short8*)&kp[c * 32 + quad * 8];
                kf[8 + c] = *(const short8*)&kp[(size_t)16 * NKV + c * 32 + quad * 8];
            }
#pragma unroll
            for (int nt = 0; nt < 16; nt++)
                vf[nt] = *(const short8*)&Vb[(size_t)(nt * 16 + lm) * SS + quad * 8];
        }

        for (int t = 0; t < T; t++) {
            const int k0 = t * 32;

            // ---- S = Q K^T (16 x 32) ----
            f32x4 sa0 = (f32x4)0.0f, sa1 = (f32x4)0.0f;
#pragma unroll
            for (int c = 0; c < 8; c++) {
                sa0 = mfma16(qf[c], kf[c],     sa0);
                sa1 = mfma16(qf[c], kf[8 + c], sa1);
            }

            // prefetch next K tile (regs free after MFMA issue)
            if (t + 1 < T) {
                const unsigned short* kp = Kb + (size_t)(k0 + 32 + lm) * NKV;
#pragma unroll
                for (int c = 0; c < 8; c++) {
                    kf[c]     = *(const short8*)&kp[c * 32 + quad * 8];
                    kf[8 + c] = *(const short8*)&kp[(size_t)16 * NKV + c * 32 + quad * 8];
                }
            }

            // ---- cubic softcap + fixed-max exp (no cross-lane) ----
            const bool diag = (t == T - 1);
            float pe[2][4];
#pragma unroll
            for (int t2 = 0; t2 < 2; t2++) {
                const int key = k0 + t2 * 16 + lm;
#pragma unroll
                for (int r = 0; r < 4; r++) {
                    float s = (t2 ? sa1[r] : sa0[r]) * SCALING;
                    s = s - s * s * s * CAPC;            // ~= SOFTCAP*tanh(s/SOFTCAP)
                    float e = __expf(s - M0);
                    if (diag && key > row + r) e = 0.0f;
                    pe[t2][r] = e;
                    l_r[r] += e;
                }
            }

            // ---- P: C layout -> A layout via per-wave LDS ----
#pragma unroll
            for (int t2 = 0; t2 < 2; t2++)
#pragma unroll
                for (int r = 0; r < 4; r++)
                    Ps[w][quad * 4 + r][t2 * 16 + lm] = f2bf(pe[t2][r]);
            asm volatile("s_waitcnt lgkmcnt(0)" ::: "memory");
            short8 pf = *(const short8*)&Ps[w][lm][quad * 8];

            // ---- O += P V ----
#pragma unroll
            for (int nt = 0; nt < 16; nt++)
                o_acc[nt] = mfma16(pf, vf[nt], o_acc[nt]);

            // prefetch next V tile
            if (t + 1 < T) {
#pragma unroll
                for (int nt = 0; nt < 16; nt++)
                    vf[nt] = *(const short8*)&Vb[(size_t)(nt * 16 + lm) * SS + k0 + 32 + quad * 8];
            }
        }

        // ---- epilogue: reduce l over the 16-lane column group, store ----
#pragma unroll
        for (int off = 1; off < 16; off <<= 1)
#pragma unroll
            for (int r = 0; r < 4; r++) l_r[r] += __shfl_xor(l_r[r], off);
#pragma unroll
        for (int r = 0; r < 4; r++) {
            float inv = 1.0f / l_r[r];
            unsigned short* Ob = O + ((size_t)b * SS + row + r) * NQ + h * HDD;
#pragma unroll
            for (int nt = 0; nt < 16; nt++)
                Ob[nt * 16 + lm] = f2bf(o_acc[nt][r] * inv);
        }
    }
}

// ---------------------------------------------------------------------------
extern "C" void kernel_launch(void* const* d_in, const int* in_sizes, int n_in,
                              void* d_out, int out_size, void* d_ws, size_t ws_size,
                              hipStream_t stream)
{
    const float* x    = (const float*)d_in[0];
    const float* cosb = (const float*)d_in[1];
    const float* sinb = (const float*)d_in[2];
    // d_in[3] = mask (pure causal + NEG, reimplemented in-kernel)
    const float* q_w  = (const float*)d_in[4];
    const float* k_w  = (const float*)d_in[5];
    const float* v_w  = (const float*)d_in[6];
    const float* o_w  = (const float*)d_in[7];
    const float* qn_w = (const float*)d_in[8];
    const float* kn_w = (const float*)d_in[9];
    float* out = (float*)d_out;

    // big-path layout (bf16 shorts), ATT aliases xb (x dead after QKV gemms)
    const size_t sz_xb = (size_t)MM * DD;     // 10485760
    const size_t sz_wq = (size_t)NQ * DD;     // 5242880
    const size_t sz_wk = (size_t)NKV * DD;    // 2621440
    const size_t sz_q  = (size_t)MM * NQ;     // 8388608
    const size_t sz_k  = (size_t)MM * NKV;    // 4194304
    const size_t need  = (sz_xb + sz_wq + 2 * sz_wk + sz_wq + sz_q + 2 * sz_k) * 2;

    if (ws_size >= need) {
        unsigned short* xb  = (unsigned short*)d_ws;
        unsigned short* wqb = xb  + sz_xb;
        unsigned short* wkb = wqb + sz_wq;
        unsigned short* wvb = wkb + sz_wk;
        unsigned short* wob = wvb + sz_wk;
        unsigned short* Qw  = wob + sz_wq;
        unsigned short* Kw  = Qw  + sz_q;
        unsigned short* VTw = Kw  + sz_k;
        unsigned short* ATT = xb;             // alias: x dead after QKV

        cvt_bf16<<<2048, 256, 0, stream>>>(x,   xb,  (int)(sz_xb / 4));
        cvt_bf16<<<2048, 256, 0, stream>>>(q_w, wqb, (int)(sz_wq / 4));
        cvt_bf16<<<1024, 256, 0, stream>>>(k_w, wkb, (int)(sz_wk / 4));
        cvt_bf16<<<1024, 256, 0, stream>>>(v_w, wvb, (int)(sz_wk / 4));
        cvt_bf16<<<2048, 256, 0, stream>>>(o_w, wob, (int)(sz_wq / 4));

        gemm_bt16<unsigned short, false><<<dim3(MM/128, NQ /128), 256, 0, stream>>>(xb, wqb, Qw,  MM, NQ,  DD);
        gemm_bt16<unsigned short, false><<<dim3(MM/128, NKV/128), 256, 0, stream>>>(xb, wkb, Kw,  MM, NKV, DD);
        gemm_bt16<unsigned short, true ><<<dim3(MM/128, NKV/128), 256, 0, stream>>>(xb, wvb, VTw, MM, NKV, DD);

        norm_rope<<<dim3(MM, HH),   256, 0, stream>>>(Qw, qn_w, cosb, sinb, HH);
        norm_rope<<<dim3(MM, HKVV), 256, 0, stream>>>(Kw, kn_w, cosb, sinb, HKVV);

        attn_kernel<<<dim3(16, HH, BB), 256, 0, stream>>>(Qw, Kw, VTw, ATT);

        gemm_bt16<float, false><<<dim3(MM/128, DD/128), 256, 0, stream>>>(ATT, wob, out, MM, DD, NQ);
    } else {
        // fallback: round-3 GEMMs (fp32 staging) + new attention
        unsigned short* Qw  = (unsigned short*)d_ws;
        unsigned short* Kw  = Qw  + sz_q;
        unsigned short* VTw = Kw  + sz_k;
        unsigned short* ATT = VTw + sz_k;

        gemm_bt   <<<dim3(MM/128, NQ /128), 256, 0, stream>>>(x, q_w, Qw,  MM, NQ,  DD);
        gemm_bt   <<<dim3(MM/128, NKV/128), 256, 0, stream>>>(x, k_w, Kw,  MM, NKV, DD);
        gemm_bt_vt<<<dim3(MM/128, NKV/128), 256, 0, stream>>>(x, v_w, VTw, MM, NKV, DD);

        norm_rope<<<dim3(MM, HH),   256, 0, stream>>>(Qw, qn_w, cosb, sinb, HH);
        norm_rope<<<dim3(MM, HKVV), 256, 0, stream>>>(Kw, kn_w, cosb, sinb, HKVV);

        attn_kernel<<<dim3(16, HH, BB), 256, 0, stream>>>(Qw, Kw, VTw, ATT);

        gemm_bt<<<dim3(MM/128, DD/128), 256, 0, stream>>>(ATT, o_w, out, MM, DD, NQ);
    }
}

// Round 5
// 579.648 us; speedup vs baseline: 2.1803x; 1.1964x over previous
//
#include <hip/hip_runtime.h>
#include <hip/hip_bf16.h>

// Problem constants
#define BB   2
#define SS   2048
#define DD   2560
#define HH   8
#define HKVV 4
#define HDD  256
#define MM   (BB*SS)      // 4096 rows
#define NQ   (HH*HDD)     // 2048
#define NKV  (HKVV*HDD)   // 1024
#define SCALING 0.0625f   // 256^-0.5
#define SOFTCAP 4096.0f
#define CAPC    (1.0f/(3.0f*SOFTCAP*SOFTCAP))  // cubic softcap coefficient
#define M0      20.0f     // fixed softmax max: |scores| <= 16.2 by Cauchy-Schwarz

typedef __attribute__((ext_vector_type(8))) short short8;       // 8 bf16 (4 VGPR)
typedef __attribute__((ext_vector_type(8))) unsigned short ushort8;
typedef __attribute__((ext_vector_type(4))) unsigned short us4;
typedef __attribute__((ext_vector_type(4))) float f32x4;        // MFMA C/D

__device__ __forceinline__ float bf2f(unsigned short u) {
    union { unsigned int i; float f; } v; v.i = ((unsigned int)u) << 16; return v.f;
}
__device__ __forceinline__ unsigned short f2bf(float f) {
    union { float f; unsigned int i; } v; v.f = f;
    return (unsigned short)((v.i + 0x7fffu + ((v.i >> 16) & 1u)) >> 16);
}
__device__ __forceinline__ f32x4 mfma16(short8 a, short8 b, f32x4 c) {
    return __builtin_amdgcn_mfma_f32_16x16x32_bf16(a, b, c, 0, 0, 0);
}

// async global->LDS, 16B per lane (gfx950). LDS dest must be tid-linear.
__device__ __forceinline__ void async_cp16(const void* g, void* l) {
    __builtin_amdgcn_global_load_lds(
        (__attribute__((address_space(1))) void*)(g),
        (__attribute__((address_space(3))) void*)(l), 16, 0, 0);
}

// dtype-polymorphic helpers
__device__ __forceinline__ ushort8 ld8(const unsigned short* p) { return *(const ushort8*)p; }
__device__ __forceinline__ ushort8 ld8(const float* p) {
    ushort8 r;
#pragma unroll
    for (int i = 0; i < 8; i++) r[i] = f2bf(p[i]);
    return r;
}
__device__ __forceinline__ void stc(float* p, float v)          { *p = v; }
__device__ __forceinline__ void stc(unsigned short* p, float v) { *p = f2bf(v); }
// staging: bf16 source -> async DMA; fp32 source -> in-reg convert + LDS write
__device__ __forceinline__ void stage8(const unsigned short* src, unsigned short* lds) {
    async_cp16(src, lds);
}
__device__ __forceinline__ void stage8(const float* src, unsigned short* lds) {
    *(ushort8*)lds = ld8(src);
}

// ---------------------------------------------------------------------------
// fp32 -> bf16 bulk convert (RNE), float4-vectorized grid-stride
// ---------------------------------------------------------------------------
__global__ __launch_bounds__(256) void cvt_bf16(const float* __restrict__ in,
                                                unsigned short* __restrict__ out, int n4)
{
    int i = blockIdx.x * 256 + threadIdx.x;
    const int stride = gridDim.x * 256;
    for (; i < n4; i += stride) {
        float4 v = ((const float4*)in)[i];
        us4 o;
        o[0] = f2bf(v.x); o[1] = f2bf(v.y); o[2] = f2bf(v.z); o[3] = f2bf(v.w);
        ((us4*)out)[i] = o;
    }
}

// ---------------------------------------------------------------------------
// Unified GEMM: C(M,N) = A(M,K) @ B(N,K)^T. bf16 operands staged via
// global_load_lds(16B); fp32 operands converted in-reg. 128x128 tile, 4
// waves. VT_OUT: epilogue writes V^T (b,kvh,d,s) instead of row-major C.
// ---------------------------------------------------------------------------
template<typename TA, typename TB, typename TC, bool VT_OUT>
__global__ __launch_bounds__(256) void gemm_k(const TA* __restrict__ A,
                                              const TB* __restrict__ Bm,
                                              TC* __restrict__ C,
                                              int M, int N, int K)
{
    __shared__ __align__(16) unsigned short As[128][32];
    __shared__ __align__(16) unsigned short Bs[128][32];

    const int tid  = threadIdx.x;
    const int bm   = blockIdx.x, bn = blockIdx.y;
    const int wave = tid >> 6, lane = tid & 63;
    const int quad = lane >> 4, lm = lane & 15;
    const int wm = (wave >> 1) * 64, wn = (wave & 1) * 64;

    f32x4 acc[4][4];
#pragma unroll
    for (int i = 0; i < 4; i++)
#pragma unroll
        for (int j = 0; j < 4; j++) acc[i][j] = (f32x4)0.0f;

    unsigned short* AsF = &As[0][0];
    unsigned short* BsF = &Bs[0][0];
    const int grow = tid >> 2;           // 0..63
    const int gcol = (tid & 3) * 8;      // 0,8,16,24
    const TA* Ab = A  + (size_t)(bm * 128) * K;
    const TB* Bb = Bm + (size_t)(bn * 128) * K;

    for (int k0 = 0; k0 < K; k0 += 32) {
        stage8(&Ab[(size_t)(grow     ) * K + k0 + gcol], AsF + tid * 8);
        stage8(&Ab[(size_t)(grow + 64) * K + k0 + gcol], AsF + 2048 + tid * 8);
        stage8(&Bb[(size_t)(grow     ) * K + k0 + gcol], BsF + tid * 8);
        stage8(&Bb[(size_t)(grow + 64) * K + k0 + gcol], BsF + 2048 + tid * 8);
        __syncthreads();   // drains vmcnt/lgkmcnt -> LDS valid

        short8 af[4], bf[4];
#pragma unroll
        for (int t = 0; t < 4; t++) af[t] = *(const short8*)&As[wm + t * 16 + lm][quad * 8];
#pragma unroll
        for (int t = 0; t < 4; t++) bf[t] = *(const short8*)&Bs[wn + t * 16 + lm][quad * 8];
#pragma unroll
        for (int i = 0; i < 4; i++)
#pragma unroll
            for (int j = 0; j < 4; j++)
                acc[i][j] = mfma16(af[i], bf[j], acc[i][j]);
        __syncthreads();
    }

    // C/D layout: row = quad*4 + r, col = lm  [verified m89/m91]
#pragma unroll
    for (int i = 0; i < 4; i++)
#pragma unroll
        for (int j = 0; j < 4; j++) {
            if constexpr (VT_OUT) {
                int row0 = bm * 128 + wm + i * 16 + quad * 4;   // b*SS + s0
                int col  = bn * 128 + wn + j * 16 + lm;         // kvh*HDD + d
                int b    = row0 >> 11, s0 = row0 & (SS - 1);
                int kvh  = col >> 8,   d  = col & (HDD - 1);
                us4 pk;
#pragma unroll
                for (int r = 0; r < 4; r++) pk[r] = f2bf(acc[i][j][r]);
                *(us4*)&C[(((size_t)b * HKVV + kvh) * HDD + d) * SS + s0] = pk;
            } else {
#pragma unroll
                for (int r = 0; r < 4; r++) {
                    int row = bm * 128 + wm + i * 16 + quad * 4 + r;
                    int col = bn * 128 + wn + j * 16 + lm;
                    stc(&C[(size_t)row * N + col], acc[i][j][r]);
                }
            }
        }
}

// ---------------------------------------------------------------------------
// Fused RMSNorm + RoPE in place on bf16 X (b, s, h, d), one block per (bs,h).
// ---------------------------------------------------------------------------
__global__ __launch_bounds__(256) void norm_rope(unsigned short* __restrict__ X,
                                                 const float* __restrict__ nw,
                                                 const float* __restrict__ cosb,
                                                 const float* __restrict__ sinb,
                                                 int nheads)
{
    const int bs = blockIdx.x;
    const int h  = blockIdx.y;
    const int t  = threadIdx.x;

    __shared__ float xs[256];
    __shared__ float red[4];

    const size_t base = ((size_t)bs * nheads + h) * HDD;
    float v = bf2f(X[base + t]);
    xs[t] = v;

    float p = v * v;
#pragma unroll
    for (int off = 32; off >= 1; off >>= 1) p += __shfl_xor(p, off);
    if ((t & 63) == 0) red[t >> 6] = p;
    __syncthreads();
    float sum = red[0] + red[1] + red[2] + red[3];
    float rs  = rsqrtf(sum * (1.0f / HDD) + 1e-6f);

    const int pt = (t + 128) & 255;
    float w1 = 1.0f + nw[t];
    float w2 = 1.0f + nw[pt];
    float normed  = v * rs * w1;
    float partner = xs[pt] * rs * w2;
    float rot = (t < 128) ? -partner : partner;   // rotate_half: [-x2, x1]
    float c = cosb[(size_t)bs * HDD + t];
    float s = sinb[(size_t)bs * HDD + t];
    X[base + t] = f2bf(normed * c + rot * s);
}

// ---------------------------------------------------------------------------
// Block-cooperative flash attention, causal, GQA, cubic softcap, fixed-max
// softmax. Block = 4 waves = 64 q-rows (16/wave). Per step, one 32-key K/V
// tile is staged in LDS via global_load_lds and shared by all 4 waves
// (L2 traffic /4 vs per-wave loads). XOR swizzles keep b128 LDS reads at
// the bank floor despite the async DMA's forced linear write layout.
// Q,K ws layout (b,s,h,d) bf16; VT (b,kvh,d,s) bf16; ATT (b,s,h*HD+d) bf16.
// ---------------------------------------------------------------------------
__global__ __launch_bounds__(256) void attn_kernel(const unsigned short* __restrict__ Q,
                                                   const unsigned short* __restrict__ K,
                                                   const unsigned short* __restrict__ VT,
                                                   unsigned short* __restrict__ O)
{
    const int tid = threadIdx.x, w = tid >> 6, lane = tid & 63;
    const int quad = lane >> 4, lm = lane & 15;
    const int h = blockIdx.y, b = blockIdx.z, kvh = h >> 1;

    // interleave heavy/light q-blocks: 0,31,1,30,...
    const int bx = blockIdx.x;                   // 0..31
    const int qb = (bx & 1) ? (31 - (bx >> 1)) : (bx >> 1);
    const int q0 = qb * 64;
    const int T  = 2 * (qb + 1);                 // 32-key tiles

    __shared__ __align__(16) unsigned short Ks[32 * 256];   // 16 KB, 64B-group swizzled
    __shared__ __align__(16) unsigned short Vt[256 * 32];   // 16 KB, (d, s) layout
    __shared__ __align__(16) unsigned short Ps[4 * 512];    // per-wave P, 16B-group swizzled

    // Q A-fragments: lane holds Q[m=lm][k=quad*8+j] per 32-wide chunk c
    const unsigned short* Qb = Q + (((size_t)b * SS + q0 + w * 16 + lm) * HH + h) * HDD;
    short8 qf[8];
#pragma unroll
    for (int c = 0; c < 8; c++) qf[c] = *(const short8*)&Qb[c * 32 + quad * 8];

    const unsigned short* Kb = K  + (size_t)b * SS * NKV + (size_t)kvh * HDD;    // row s, stride NKV
    const unsigned short* Vb = VT + ((size_t)b * HKVV + kvh) * HDD * (size_t)SS; // row d, stride SS

    f32x4 o_acc[16];
#pragma unroll
    for (int i = 0; i < 16; i++) o_acc[i] = (f32x4)0.0f;
    float l_r[4] = {0.f, 0.f, 0.f, 0.f};

    const int mylo = q0 + w * 16;                // wave's first q-row
    const int row  = mylo + quad * 4;            // + r = C-layout rows

    for (int t = 0; t < T; t++) {
        const int k0 = t * 32;

        // ---- stage K (row-major, 64B-swizzled) and V^T tiles ----
#pragma unroll
        for (int p = 0; p < 4; p++) {
            const int slot = p * 256 + tid;
            // K: LDS row krow holds global 64B-group g at position g^(krow&7)
            const int krow = slot >> 5, kc = slot & 31;
            const int g = kc >> 2, win = kc & 3;
            async_cp16(&Kb[(size_t)(k0 + krow) * NKV + (((g ^ (krow & 7)) << 2) + win) * 8],
                       Ks + slot * 8);
            // V^T: row d (32 shorts = 64B), contiguous keys
            const int vd = slot >> 2, vc = slot & 3;
            async_cp16(&Vb[(size_t)vd * SS + k0 + vc * 8], Vt + slot * 8);
        }
        __syncthreads();

        if (k0 <= mylo + 15) {                   // wave has unmasked keys (wave-uniform)
            // ---- S = Q K^T (16 x 32) ----
            f32x4 sa0 = (f32x4)0.0f, sa1 = (f32x4)0.0f;
#pragma unroll
            for (int c = 0; c < 8; c++) {
                const int cs = ((c ^ (lm & 7)) * 4 + quad) * 8;   // un-swizzle
                short8 kf0 = *(const short8*)&Ks[lm * 256 + cs];
                short8 kf1 = *(const short8*)&Ks[(16 + lm) * 256 + cs];
                sa0 = mfma16(qf[c], kf0, sa0);
                sa1 = mfma16(qf[c], kf1, sa1);
            }

            // ---- cubic softcap + fixed-max exp (no cross-lane) ----
            const bool msk = (k0 + 31 > mylo);
            float pe[2][4];
#pragma unroll
            for (int t2 = 0; t2 < 2; t2++) {
                const int key = k0 + t2 * 16 + lm;
#pragma unroll
                for (int r = 0; r < 4; r++) {
                    float s = (t2 ? sa1[r] : sa0[r]) * SCALING;
                    s = s - s * s * s * CAPC;            // ~= SOFTCAP*tanh(s/SOFTCAP)
                    float e = __expf(s - M0);
                    if (msk && key > row + r) e = 0.0f;
                    pe[t2][r] = e;
                    l_r[r] += e;
                }
            }

            // ---- P: C layout -> A layout via swizzled per-wave LDS ----
#pragma unroll
            for (int t2 = 0; t2 < 2; t2++)
#pragma unroll
                for (int r = 0; r < 4; r++) {
                    const int g = (t2 * 2 + (lm >> 3)) ^ r ^ quad;
                    Ps[w * 512 + (quad * 4 + r) * 32 + g * 8 + (lm & 7)] = f2bf(pe[t2][r]);
                }
            asm volatile("s_waitcnt lgkmcnt(0)" ::: "memory");
            const int gr = quad ^ (lm & 3) ^ (lm >> 2);
            short8 pf = *(const short8*)&Ps[w * 512 + lm * 32 + gr * 8];

            // ---- O += P V ----
#pragma unroll
            for (int nt = 0; nt < 16; nt++) {
                short8 vf = *(const short8*)&Vt[(nt * 16 + lm) * 32 + quad * 8];
                o_acc[nt] = mfma16(pf, vf, o_acc[nt]);
            }
        }
        __syncthreads();
    }

    // ---- epilogue: reduce l over 16-lane col group, normalize, store ----
#pragma unroll
    for (int off = 1; off < 16; off <<= 1)
#pragma unroll
        for (int r = 0; r < 4; r++) l_r[r] += __shfl_xor(l_r[r], off);
#pragma unroll
    for (int r = 0; r < 4; r++) {
        float inv = 1.0f / l_r[r];
        unsigned short* Ob = O + ((size_t)b * SS + row + r) * NQ + h * HDD;
#pragma unroll
        for (int nt = 0; nt < 16; nt++)
            Ob[nt * 16 + lm] = f2bf(o_acc[nt][r] * inv);
    }
}

// ---------------------------------------------------------------------------
extern "C" void kernel_launch(void* const* d_in, const int* in_sizes, int n_in,
                              void* d_out, int out_size, void* d_ws, size_t ws_size,
                              hipStream_t stream)
{
    const float* x    = (const float*)d_in[0];
    const float* cosb = (const float*)d_in[1];
    const float* sinb = (const float*)d_in[2];
    // d_in[3] = mask (pure causal + NEG, reimplemented in-kernel)
    const float* q_w  = (const float*)d_in[4];
    const float* k_w  = (const float*)d_in[5];
    const float* v_w  = (const float*)d_in[6];
    const float* o_w  = (const float*)d_in[7];
    const float* qn_w = (const float*)d_in[8];
    const float* kn_w = (const float*)d_in[9];
    float* out = (float*)d_out;

    const size_t sz_xb = (size_t)MM * DD;     // 10485760 shorts
    const size_t sz_wq = (size_t)NQ * DD;     //  5242880
    const size_t sz_wk = (size_t)NKV * DD;    //  2621440
    const size_t sz_q  = (size_t)MM * NQ;     //  8388608
    const size_t sz_k  = (size_t)MM * NKV;    //  4194304

    const size_t needA = (sz_xb + 2 * sz_wq + 2 * sz_wk + sz_q + 2 * sz_k) * 2; // ~86 MB
    const size_t needB = (2 * sz_wq + 2 * sz_wk + sz_q + 2 * sz_k) * 2;         // ~65 MB

    if (ws_size >= needA) {
        // Tier A: everything bf16, all-async GEMMs
        unsigned short* xb  = (unsigned short*)d_ws;
        unsigned short* wqb = xb  + sz_xb;
        unsigned short* wkb = wqb + sz_wq;
        unsigned short* wvb = wkb + sz_wk;
        unsigned short* wob = wvb + sz_wk;
        unsigned short* Qw  = wob + sz_wq;
        unsigned short* Kw  = Qw  + sz_q;
        unsigned short* VTw = Kw  + sz_k;
        unsigned short* ATT = xb;             // alias: x dead after QKV

        cvt_bf16<<<2048, 256, 0, stream>>>(x,   xb,  (int)(sz_xb / 4));
        cvt_bf16<<<2048, 256, 0, stream>>>(q_w, wqb, (int)(sz_wq / 4));
        cvt_bf16<<<1024, 256, 0, stream>>>(k_w, wkb, (int)(sz_wk / 4));
        cvt_bf16<<<1024, 256, 0, stream>>>(v_w, wvb, (int)(sz_wk / 4));
        cvt_bf16<<<2048, 256, 0, stream>>>(o_w, wob, (int)(sz_wq / 4));

        gemm_k<unsigned short, unsigned short, unsigned short, false>
            <<<dim3(MM/128, NQ /128), 256, 0, stream>>>(xb, wqb, Qw,  MM, NQ,  DD);
        gemm_k<unsigned short, unsigned short, unsigned short, false>
            <<<dim3(MM/128, NKV/128), 256, 0, stream>>>(xb, wkb, Kw,  MM, NKV, DD);
        gemm_k<unsigned short, unsigned short, unsigned short, true>
            <<<dim3(MM/128, NKV/128), 256, 0, stream>>>(xb, wvb, VTw, MM, NKV, DD);

        norm_rope<<<dim3(MM, HH),   256, 0, stream>>>(Qw, qn_w, cosb, sinb, HH);
        norm_rope<<<dim3(MM, HKVV), 256, 0, stream>>>(Kw, kn_w, cosb, sinb, HKVV);

        attn_kernel<<<dim3(32, HH, BB), 256, 0, stream>>>(Qw, Kw, VTw, ATT);

        gemm_k<unsigned short, unsigned short, float, false>
            <<<dim3(MM/128, DD/128), 256, 0, stream>>>(ATT, wob, out, MM, DD, NQ);
    } else if (ws_size >= needB) {
        // Tier B: weights bf16; x staged fp32->bf16 in GEMM; ATT reuses wq/wk/wv
        unsigned short* wqb = (unsigned short*)d_ws;
        unsigned short* wkb = wqb + sz_wq;
        unsigned short* wvb = wkb + sz_wk;
        unsigned short* wob = wvb + sz_wk;
        unsigned short* Qw  = wob + sz_wq;
        unsigned short* Kw  = Qw  + sz_q;
        unsigned short* VTw = Kw  + sz_k;
        unsigned short* ATT = wqb;            // alias: wq/wk/wv dead after QKV

        cvt_bf16<<<2048, 256, 0, stream>>>(q_w, wqb, (int)(sz_wq / 4));
        cvt_bf16<<<1024, 256, 0, stream>>>(k_w, wkb, (int)(sz_wk / 4));
        cvt_bf16<<<1024, 256, 0, stream>>>(v_w, wvb, (int)(sz_wk / 4));
        cvt_bf16<<<2048, 256, 0, stream>>>(o_w, wob, (int)(sz_wq / 4));

        gemm_k<float, unsigned short, unsigned short, false>
            <<<dim3(MM/128, NQ /128), 256, 0, stream>>>(x, wqb, Qw,  MM, NQ,  DD);
        gemm_k<float, unsigned short, unsigned short, false>
            <<<dim3(MM/128, NKV/128), 256, 0, stream>>>(x, wkb, Kw,  MM, NKV, DD);
        gemm_k<float, unsigned short, unsigned short, true>
            <<<dim3(MM/128, NKV/128), 256, 0, stream>>>(x, wvb, VTw, MM, NKV, DD);

        norm_rope<<<dim3(MM, HH),   256, 0, stream>>>(Qw, qn_w, cosb, sinb, HH);
        norm_rope<<<dim3(MM, HKVV), 256, 0, stream>>>(Kw, kn_w, cosb, sinb, HKVV);

        attn_kernel<<<dim3(32, HH, BB), 256, 0, stream>>>(Qw, Kw, VTw, ATT);

        gemm_k<unsigned short, unsigned short, float, false>
            <<<dim3(MM/128, DD/128), 256, 0, stream>>>(ATT, wob, out, MM, DD, NQ);
    } else {
        // Tier C: fp32 operands staged with in-reg convert (round-3 style)
        unsigned short* Qw  = (unsigned short*)d_ws;
        unsigned short* Kw  = Qw  + sz_q;
        unsigned short* VTw = Kw  + sz_k;
        unsigned short* ATT = VTw + sz_k;

        gemm_k<float, float, unsigned short, false>
            <<<dim3(MM/128, NQ /128), 256, 0, stream>>>(x, q_w, Qw,  MM, NQ,  DD);
        gemm_k<float, float, unsigned short, false>
            <<<dim3(MM/128, NKV/128), 256, 0, stream>>>(x, k_w, Kw,  MM, NKV, DD);
        gemm_k<float, float, unsigned short, true>
            <<<dim3(MM/128, NKV/128), 256, 0, stream>>>(x, v_w, VTw, MM, NKV, DD);

        norm_rope<<<dim3(MM, HH),   256, 0, stream>>>(Qw, qn_w, cosb, sinb, HH);
        norm_rope<<<dim3(MM, HKVV), 256, 0, stream>>>(Kw, kn_w, cosb, sinb, HKVV);

        attn_kernel<<<dim3(32, HH, BB), 256, 0, stream>>>(Qw, Kw, VTw, ATT);

        gemm_k<unsigned short, float, float, false>
            <<<dim3(MM/128, DD/128), 256, 0, stream>>>(ATT, o_w, out, MM, DD, NQ);
    }
}